// Round 16
// baseline (281.195 us; speedup 1.0000x reference)
//
#include <hip/hip_runtime.h>

#define N_PREV 250000
#define N_FULL 500000
#define NVOX   65536
#define NWORDS (1u<<20)          // bitmap words; keyspace < 2^25 bits
#define EPSF   1e-5f

typedef __attribute__((ext_vector_type(4)))  short short4v;
typedef __attribute__((ext_vector_type(8)))  short short8v;
typedef __attribute__((ext_vector_type(16))) float f32x16;

__device__ __forceinline__ float lrelu(float x){ return x > 0.0f ? x : 0.1f*x; }
__device__ __forceinline__ short f2bf_rne(float v){
    unsigned u = __float_as_uint(v);
    unsigned r = (u + 0x7fffu + ((u>>16)&1u)) >> 16;
    return (short)r;
}
__device__ __forceinline__ float bf2f(short s){
    return __uint_as_float(((unsigned)(unsigned short)s) << 16);
}

// ---------------- ws layout (bytes) ----------------
// zeroed prefix:
#define OFF_BITMAP   0ul            // u32[NWORDS] (aliased as csr_j/csr_h after k_p1f)
#define OFF_STATS    4194304ul      // f32[256]
#define OFF_CNT      4195328ul      // f32[N_PREV]
#define OFF_VH       5195328ul      // u32[NVOX]
#define OFF_Y        5457472ul      // bf16[N_PREV*32]  16 MB  (dead after ppm2; T aliases here)
#define ZERO_BYTES   21457472ul
// not zeroed:
#define OFF_T        5457472ul      // f32[NVOX*64] 16.78 MB (k_vox -> k_wo2; after yb dead)
#define OFF_P2       37457472ul     // bf16[N_PREV*64] 32 MB
#define OFF_PREF     69457472ul     // u32[NWORDS] (aliased as vstart/vnext/vpart/vbsum after p1f)
#define OFF_BSUM     73651776ul
#define OFF_BOFF     73655872ul
#define OFF_UCNT     73659968ul
#define OFF_INV      73660224ul     // i32[N_PREV]
#define OFF_P1       74660224ul     // bf16[N_PREV*64] 32 MB
#define OFF_X2       106660224ul    // bf16[N_PREV*32] 16 MB (x2b: first written by ppm2;
                                    //   wfrag parks in its head until k_p1f is done)
#define WS_NEEDED    138660224ul
#define OFF_CSRJ     0ul
#define OFF_CSRH     2000000ul
#define OFF_VSTART   69457472ul
#define OFF_VNEXT    (OFF_VSTART+262400ul)
#define OFF_VPART    (OFF_VNEXT+262144ul)
#define OFF_VBSUM    (OFF_VPART+262144ul)
#define OFF_WFRAG    OFF_X2         // 80 KB; liveness: wprep -> p1f, before ppm2 writes x2b

__device__ __forceinline__ int voxel_key(int4 c){
    return ((c.x*501 + (c.y>>1))*501 + (c.z>>1))*31 + (c.w>>1);
}

// ---- one-block setup: build k_p1f's per-thread weight fragments once ----
__global__ void __launch_bounds__(256) k_wprep(const float* __restrict__ Win,
        const float* __restrict__ Wo1, const float* __restrict__ W1,
        short* __restrict__ wfrag){
    __shared__ __align__(16) short Ah[64*68];
    __shared__ __align__(16) short Al[64*68];
    int tid = threadIdx.x;
    int wave = tid >> 6, l = tid & 63;
    int g = l >> 5, c = l & 31;
    int colhalf = (wave & 1) * 32;

    short8v w1h[4], w1l[4], w2h[4], w0h[4], w0l[4];

    // stage Win^T (hi/lo)
    {
        int col = tid >> 2, kseg = (tid & 3) * 16;
        short hi[16], lo[16];
        #pragma unroll
        for(int j=0;j<16;++j){
            float v = Win[(kseg+j)*64 + col];
            short h = f2bf_rne(v);
            hi[j] = h; lo[j] = f2bf_rne(v - bf2f(h));
        }
        #pragma unroll
        for(int i=0;i<4;++i){
            *(short4v*)&Ah[col*68 + kseg + 4*i] = *(short4v*)&hi[4*i];
            *(short4v*)&Al[col*68 + kseg + 4*i] = *(short4v*)&lo[4*i];
        }
    }
    __syncthreads();
    #pragma unroll
    for(int s=0;s<4;++s){
        int base = (colhalf + c)*68 + s*16 + g*4;
        ((short4v*)&w1h[s])[0] = *(short4v*)&Ah[base];
        ((short4v*)&w1h[s])[1] = *(short4v*)&Ah[base + 8];
        ((short4v*)&w1l[s])[0] = *(short4v*)&Al[base];
        ((short4v*)&w1l[s])[1] = *(short4v*)&Al[base + 8];
    }
    __syncthreads();
    // stage Wo1a^T (hi only)
    {
        int col = tid >> 2, kseg = (tid & 3) * 16;
        short hi[16];
        #pragma unroll
        for(int j=0;j<16;++j) hi[j] = f2bf_rne(Wo1[(kseg+j)*64 + col]);
        #pragma unroll
        for(int i=0;i<4;++i)
            *(short4v*)&Ah[col*68 + kseg + 4*i] = *(short4v*)&hi[4*i];
    }
    __syncthreads();
    #pragma unroll
    for(int s=0;s<4;++s){
        int base = (colhalf + c)*68 + s*16 + g*4;
        ((short4v*)&w2h[s])[0] = *(short4v*)&Ah[base];
        ((short4v*)&w2h[s])[1] = *(short4v*)&Ah[base + 8];
    }
    __syncthreads();
    // stage W1^T [32 col][64 k] (hi/lo)
    if(tid < 128){
        int col = tid >> 2, kseg = (tid & 3) * 16;
        short hi[16], lo[16];
        #pragma unroll
        for(int j=0;j<16;++j){
            float v = W1[(kseg+j)*32 + col];
            short h = f2bf_rne(v);
            hi[j] = h; lo[j] = f2bf_rne(v - bf2f(h));
        }
        #pragma unroll
        for(int i=0;i<4;++i){
            *(short4v*)&Ah[col*68 + kseg + 4*i] = *(short4v*)&hi[4*i];
            *(short4v*)&Al[col*68 + kseg + 4*i] = *(short4v*)&lo[4*i];
        }
    }
    __syncthreads();
    #pragma unroll
    for(int s=0;s<4;++s){
        int base = c*68 + s*16 + g*4;
        ((short4v*)&w0h[s])[0] = *(short4v*)&Ah[base];
        ((short4v*)&w0h[s])[1] = *(short4v*)&Ah[base + 8];
        ((short4v*)&w0l[s])[0] = *(short4v*)&Al[base];
        ((short4v*)&w0l[s])[1] = *(short4v*)&Al[base + 8];
    }
    // store: 20 short8v per thread
    short8v* out = (short8v*)(wfrag + (size_t)tid*160);
    #pragma unroll
    for(int s=0;s<4;++s){
        out[s]      = w1h[s];
        out[4+s]    = w1l[s];
        out[8+s]    = w2h[s];
        out[12+s]   = w0h[s];
        out[16+s]   = w0l[s];
    }
}

// ---- mark present keys + voxel histogram (fused; independent scatters) ----
__global__ void k_mark(const int* __restrict__ coors, const int* __restrict__ scv,
                       unsigned* __restrict__ bitmap, unsigned* __restrict__ vh){
    int i = blockIdx.x*256 + threadIdx.x;
    if(i < N_PREV){
        int4 c = ((const int4*)coors)[i];
        int key = voxel_key(c);
        atomicOr(&bitmap[key>>5], 1u<<(key&31));
    }
    if(i < N_FULL) atomicAdd(&vh[scv[i]], 1u);
}

__global__ void __launch_bounds__(1024) k_scanA(const unsigned* __restrict__ bitmap,
                                                unsigned* __restrict__ pref,
                                                unsigned* __restrict__ bsum){
    __shared__ unsigned sh[1024];
    int tid = threadIdx.x;
    int w = blockIdx.x*1024 + tid;
    unsigned p = __popc(bitmap[w]);
    sh[tid] = p; __syncthreads();
    for(int off=1; off<1024; off<<=1){
        unsigned v = (tid>=off) ? sh[tid-off] : 0u;
        __syncthreads();
        sh[tid] += v;
        __syncthreads();
    }
    pref[w] = sh[tid] - p;
    if(tid==1023) bsum[blockIdx.x] = sh[tid];
}

__global__ void __launch_bounds__(1024) k_scanB(const unsigned* __restrict__ bsum,
                                                unsigned* __restrict__ boff,
                                                unsigned* __restrict__ Ucnt){
    __shared__ unsigned sh[1024];
    int tid = threadIdx.x;
    unsigned p = bsum[tid];
    sh[tid] = p; __syncthreads();
    for(int off=1; off<1024; off<<=1){
        unsigned v = (tid>=off) ? sh[tid-off] : 0u;
        __syncthreads();
        sh[tid] += v;
        __syncthreads();
    }
    boff[tid] = sh[tid] - p;
    if(tid==1023) Ucnt[0] = sh[tid];
}

// ---- CSR build over scale voxels ----
__global__ void __launch_bounds__(1024) k_vscanA(const unsigned* __restrict__ vh,
                                                 unsigned* __restrict__ vpart,
                                                 unsigned* __restrict__ vbsum){
    __shared__ unsigned sh[1024];
    int tid = threadIdx.x;
    int w = blockIdx.x*1024 + tid;
    unsigned p = vh[w];
    sh[tid] = p; __syncthreads();
    for(int off=1; off<1024; off<<=1){
        unsigned v = (tid>=off) ? sh[tid-off] : 0u;
        __syncthreads();
        sh[tid] += v;
        __syncthreads();
    }
    vpart[w] = sh[tid] - p;
    if(tid==1023) vbsum[blockIdx.x] = sh[tid];
}

// vscanB folded in: wave 0 redundantly scans the 64 block sums
__global__ void __launch_bounds__(1024) k_vfix(const unsigned* __restrict__ vpart,
                                               const unsigned* __restrict__ vbsum,
                                               unsigned* __restrict__ vstart,
                                               unsigned* __restrict__ vnext){
    __shared__ unsigned bo[64];
    int tid = threadIdx.x;
    if(tid < 64){
        unsigned v = vbsum[tid], orig = v;
        for(int off=1; off<64; off<<=1){
            unsigned o = __shfl_up(v, off);
            if(tid>=off) v += o;
        }
        bo[tid] = v - orig;   // exclusive
    }
    __syncthreads();
    int w = blockIdx.x*1024 + tid;
    unsigned s = vpart[w] + bo[w>>10];
    vstart[w] = s; vnext[w] = s;
    if(w == NVOX-1) vstart[NVOX] = N_FULL;
}

__global__ void k_fill(const int* __restrict__ cif, const int* __restrict__ scv,
                       const int* __restrict__ inv, unsigned* __restrict__ vnext,
                       int* __restrict__ csr_j, int* __restrict__ csr_h){
    int p = blockIdx.x*256 + threadIdx.x;
    if(p >= N_FULL) return;
    int jp = cif[p];
    unsigned pos = atomicAdd(&vnext[scv[p]], 1u);
    csr_j[pos] = jp;
    csr_h[pos] = inv[jp];
}

// ---- fused: P1 = lrelu(F@Win+b)@Wo1a (bf16 out, single-pass GEMM2);
//      Y = F@W1 3-pass, pk bf16 atomic scatter; rank/inv/cnt inline.
//      Weight fragments preloaded from wfrag (k_wprep) — barrier-free prologue. ----
__global__ void __launch_bounds__(256) k_p1f(const float* __restrict__ feat,
        const int* __restrict__ coors, const unsigned* __restrict__ bitmap,
        const unsigned* __restrict__ pref, const unsigned* __restrict__ boff,
        const float* __restrict__ bin, const short* __restrict__ wfrag,
        unsigned short* __restrict__ P1, int* __restrict__ inv,
        float* __restrict__ cnt, unsigned short* __restrict__ yb){
    __shared__ __align__(16) short Ah[64*68];
    __shared__ __align__(16) short Al[64*68];
    __shared__ float ysh[64][33];
    __shared__ int rksh[64];
    int tid = threadIdx.x;
    int wave = tid >> 6, l = tid & 63;
    int g = l >> 5, c = l & 31;
    int rowhalf = (wave >> 1) * 32, colhalf = (wave & 1) * 32;

    // load precomputed fragments (no barriers, no LDS)
    short8v w1h[4], w1l[4], w2h[4], w0h[4], w0l[4];
    {
        const short8v* wf = (const short8v*)(wfrag + (size_t)tid*160);
        #pragma unroll
        for(int s=0;s<4;++s){
            w1h[s] = wf[s];
            w1l[s] = wf[4+s];
            w2h[s] = wf[8+s];
            w0h[s] = wf[12+s];
            w0l[s] = wf[16+s];
        }
    }
    float bc1 = bin[colhalf + c];

    const int NT = (N_PREV + 63) / 64;
    for(int tile = blockIdx.x; tile < NT; tile += gridDim.x){
        int rbase = tile * 64;
        // stage F tile hi/lo
        {
            int row = tid >> 2, kseg = (tid & 3) * 16;
            int grow = rbase + row;
            float fv[16];
            if(grow < N_PREV){
                const float4* fp = (const float4*)&feat[grow*64 + kseg];
                *(float4*)&fv[0]  = fp[0];
                *(float4*)&fv[4]  = fp[1];
                *(float4*)&fv[8]  = fp[2];
                *(float4*)&fv[12] = fp[3];
            } else {
                #pragma unroll
                for(int j=0;j<16;++j) fv[j]=0.f;
            }
            short hi[16], lo[16];
            #pragma unroll
            for(int j=0;j<16;++j){
                short h = f2bf_rne(fv[j]);
                hi[j] = h; lo[j] = f2bf_rne(fv[j] - bf2f(h));
            }
            #pragma unroll
            for(int i=0;i<4;++i){
                *(short4v*)&Ah[row*68 + kseg + 4*i] = *(short4v*)&hi[4*i];
                *(short4v*)&Al[row*68 + kseg + 4*i] = *(short4v*)&lo[4*i];
            }
        }
        // ranks for this tile's rows
        if(tid < 64){
            int grow = rbase + tid;
            if(grow < N_PREV){
                int4 c4 = ((const int4*)coors)[grow];
                int key = voxel_key(c4);
                int w = key>>5, b = key&31;
                int rank = (int)(boff[w>>10] + pref[w]) + __popc(bitmap[w] & ((1u<<b)-1u));
                rksh[tid] = rank;
                inv[grow] = rank;
                atomicAdd(&cnt[rank], 1.0f);
            } else rksh[tid] = -1;
        }
        __syncthreads();
        // GEMM1: I = lrelu(F@Win + b)  (3-pass, all waves)
        f32x16 acc;
        #pragma unroll
        for(int i=0;i<16;++i) acc[i]=0.f;
        #pragma unroll
        for(int s=0;s<4;++s){
            int abase = (rowhalf + c)*68 + s*16 + g*4;
            short8v ah, al;
            ((short4v*)&ah)[0] = *(short4v*)&Ah[abase];
            ((short4v*)&ah)[1] = *(short4v*)&Ah[abase + 8];
            ((short4v*)&al)[0] = *(short4v*)&Al[abase];
            ((short4v*)&al)[1] = *(short4v*)&Al[abase + 8];
            acc = __builtin_amdgcn_mfma_f32_32x32x16_bf16(ah, w1h[s], acc, 0,0,0);
            acc = __builtin_amdgcn_mfma_f32_32x32x16_bf16(al, w1h[s], acc, 0,0,0);
            acc = __builtin_amdgcn_mfma_f32_32x32x16_bf16(ah, w1l[s], acc, 0,0,0);
        }
        // GEMM0: Y = F@W1  (3-pass, waves 0/1)
        f32x16 accY;
        #pragma unroll
        for(int i=0;i<16;++i) accY[i]=0.f;
        if(wave < 2){
            #pragma unroll
            for(int s=0;s<4;++s){
                int abase = (wave*32 + c)*68 + s*16 + g*4;
                short8v ah, al;
                ((short4v*)&ah)[0] = *(short4v*)&Ah[abase];
                ((short4v*)&ah)[1] = *(short4v*)&Ah[abase + 8];
                ((short4v*)&al)[0] = *(short4v*)&Al[abase];
                ((short4v*)&al)[1] = *(short4v*)&Al[abase + 8];
                accY = __builtin_amdgcn_mfma_f32_32x32x16_bf16(ah, w0h[s], accY, 0,0,0);
                accY = __builtin_amdgcn_mfma_f32_32x32x16_bf16(al, w0h[s], accY, 0,0,0);
                accY = __builtin_amdgcn_mfma_f32_32x32x16_bf16(ah, w0l[s], accY, 0,0,0);
            }
        }
        __syncthreads();
        // epilogue: I-hi -> Ah; Y -> ysh
        #pragma unroll
        for(int r=0;r<16;++r){
            int row = rowhalf + (r&3) + 8*(r>>2) + 4*g;
            float v = acc[r] + bc1;
            v = v > 0.f ? v : 0.1f*v;
            Ah[row*68 + colhalf + c] = f2bf_rne(v);
        }
        if(wave < 2){
            #pragma unroll
            for(int r=0;r<16;++r){
                int row = wave*32 + (r&3) + 8*(r>>2) + 4*g;
                ysh[row][c] = accY[r];
            }
        }
        __syncthreads();
        // GEMM2: P1 = I @ Wo1a  (single-pass; P1 stored bf16 anyway)
        f32x16 acc2;
        #pragma unroll
        for(int i=0;i<16;++i) acc2[i]=0.f;
        #pragma unroll
        for(int s=0;s<4;++s){
            int abase = (rowhalf + c)*68 + s*16 + g*4;
            short8v ah;
            ((short4v*)&ah)[0] = *(short4v*)&Ah[abase];
            ((short4v*)&ah)[1] = *(short4v*)&Ah[abase + 8];
            acc2 = __builtin_amdgcn_mfma_f32_32x32x16_bf16(ah, w2h[s], acc2, 0,0,0);
        }
        #pragma unroll
        for(int r=0;r<16;++r){
            int grow = rbase + rowhalf + (r&3) + 8*(r>>2) + 4*g;
            if(grow < N_PREV) P1[grow*64 + colhalf + c] = (unsigned short)f2bf_rne(acc2[r]);
        }
        // scatter Y tile into yb by rank (packed bf16 atomics: 2 channels/op)
        #pragma unroll
        for(int q=0;q<4;++q){
            int e = q*256 + tid;          // 64 rows x 16 pairs
            int row = e >> 4, pr = e & 15;
            int rk = rksh[row];
            if(rk >= 0){
                unsigned h0 = (unsigned)(unsigned short)f2bf_rne(ysh[row][2*pr]);
                unsigned h1 = (unsigned)(unsigned short)f2bf_rne(ysh[row][2*pr+1]);
                unsigned pk = h0 | (h1 << 16);
                unsigned short* addr = yb + (size_t)rk*32 + 2*pr;
                asm volatile("global_atomic_pk_add_bf16 %0, %1, off"
                             :: "v"(addr), "v"(pk) : "memory");
            }
        }
        __syncthreads();
    }
}

// ---- BN1 stats over x1 = lrelu(y/cnt + b1)  (stats only; y is bf16) ----
__global__ void __launch_bounds__(256) k_bn1(const unsigned short* __restrict__ yb,
        const float* __restrict__ cnt, const unsigned* __restrict__ Ucnt,
        const float* __restrict__ b1, float* __restrict__ stats){
    __shared__ float sst[32], qst[32];
    int tid = threadIdx.x;
    if(tid < 32){ sst[tid]=0.f; qst[tid]=0.f; }
    __syncthreads();
    int U = (int)Ucnt[0];
    int total = U*4;                 // uint4 (8 bf16) per element
    int c8 = (tid&3)*8;
    float bb[8];
    #pragma unroll
    for(int j=0;j<8;++j) bb[j] = b1[c8+j];
    float s[8], q[8];
    #pragma unroll
    for(int j=0;j<8;++j){ s[j]=0.f; q[j]=0.f; }
    for(int e = blockIdx.x*256 + tid; e < total; e += gridDim.x*256){
        int row = e >> 2;
        float rv = 1.0f/cnt[row];
        uint4 a = ((const uint4*)yb)[e];
        unsigned wv[4] = {a.x,a.y,a.z,a.w};
        #pragma unroll
        for(int k=0;k<4;++k){
            float lo = __uint_as_float(wv[k]<<16);
            float hi = __uint_as_float(wv[k]&0xffff0000u);
            float v0 = lrelu(lo*rv + bb[2*k]);
            float v1 = lrelu(hi*rv + bb[2*k+1]);
            s[2*k]+=v0; q[2*k]+=v0*v0;
            s[2*k+1]+=v1; q[2*k+1]+=v1*v1;
        }
    }
    #pragma unroll
    for(int j=0;j<8;++j){ atomicAdd(&sst[c8+j], s[j]); atomicAdd(&qst[c8+j], q[j]); }
    __syncthreads();
    if(tid < 32){ atomicAdd(&stats[tid], sst[tid]); atomicAdd(&stats[32+tid], qst[tid]); }
}

// ---- x2 = lrelu(BN1(lrelu(y/cnt+b1)) @ W2 + b2) (bf16 out), BN2 stats.
//      BN1 params computed per-block from raw sums (bnfin inlined). ----
__global__ void __launch_bounds__(256) k_ppm2(const unsigned short* __restrict__ yb,
        const float* __restrict__ cnt, const unsigned* __restrict__ Ucnt,
        const float* __restrict__ W2, const float* __restrict__ b1i,
        const float* __restrict__ b2, const float* __restrict__ be1,
        const float* __restrict__ g1, unsigned short* __restrict__ x2b,
        float* __restrict__ stats){
    __shared__ __align__(16) short Ah[128*36];
    __shared__ __align__(16) short Al[128*36];
    __shared__ float ash[32], bbsh[32], b1sh[32];
    __shared__ float red[4][64];
    int tid = threadIdx.x;
    int wave = tid >> 6, l = tid & 63;
    int g = l >> 5, c = l & 31;

    if(tid < 32){
        float n = (float)max(Ucnt[0], 1u);
        float mu = stats[tid]/n;
        float var = stats[32+tid]/n - mu*mu;
        float sc = g1[tid]*rsqrtf(var + EPSF);
        ash[tid]=sc; bbsh[tid]=be1[tid]-mu*sc;
        b1sh[tid]=b1i[tid];
    }
    if(tid >= 64 && tid < 128){
        int t = tid - 64;
        int col = t >> 1, kseg = (t & 1) * 16;
        short hi[16], lo[16];
        #pragma unroll
        for(int j=0;j<16;++j){
            float v = W2[(kseg+j)*32 + col];
            short h = f2bf_rne(v);
            hi[j] = h; lo[j] = f2bf_rne(v - bf2f(h));
        }
        #pragma unroll
        for(int i=0;i<4;++i){
            *(short4v*)&Ah[col*36 + kseg + 4*i] = *(short4v*)&hi[4*i];
            *(short4v*)&Al[col*36 + kseg + 4*i] = *(short4v*)&lo[4*i];
        }
    }
    __syncthreads();
    short8v wh[2], wl[2];
    #pragma unroll
    for(int s=0;s<2;++s){
        int base = c*36 + s*16 + g*4;
        ((short4v*)&wh[s])[0] = *(short4v*)&Ah[base];
        ((short4v*)&wh[s])[1] = *(short4v*)&Ah[base + 8];
        ((short4v*)&wl[s])[0] = *(short4v*)&Al[base];
        ((short4v*)&wl[s])[1] = *(short4v*)&Al[base + 8];
    }
    __syncthreads();

    int U = (int)Ucnt[0];
    float bc = b2[c];
    float s_acc = 0.f, q_acc = 0.f;

    const int NT = (N_PREV + 127) / 128;
    for(int tile = blockIdx.x; tile < NT; tile += gridDim.x){
        int rbase = tile * 128;
        if(rbase >= U) break;
        {
            int row = tid >> 1, kseg = (tid & 1) * 16;
            int grow = rbase + row;
            float fv[16];
            if(grow < U){
                float rv = 1.0f/cnt[grow];
                uint4 a0 = *(const uint4*)&yb[grow*32 + kseg];
                uint4 a1 = *(const uint4*)&yb[grow*32 + kseg + 8];
                unsigned wv[8] = {a0.x,a0.y,a0.z,a0.w,a1.x,a1.y,a1.z,a1.w};
                #pragma unroll
                for(int k=0;k<8;++k){
                    float lo = __uint_as_float(wv[k]<<16);
                    float hi = __uint_as_float(wv[k]&0xffff0000u);
                    float v0 = lrelu(lo*rv + b1sh[kseg+2*k]);
                    float v1 = lrelu(hi*rv + b1sh[kseg+2*k+1]);
                    fv[2*k]   = v0*ash[kseg+2*k]   + bbsh[kseg+2*k];
                    fv[2*k+1] = v1*ash[kseg+2*k+1] + bbsh[kseg+2*k+1];
                }
            } else {
                #pragma unroll
                for(int j=0;j<16;++j) fv[j]=0.f;
            }
            short hi[16], lo[16];
            #pragma unroll
            for(int j=0;j<16;++j){
                short h = f2bf_rne(fv[j]);
                hi[j] = h; lo[j] = f2bf_rne(fv[j] - bf2f(h));
            }
            #pragma unroll
            for(int i=0;i<4;++i){
                *(short4v*)&Ah[row*36 + kseg + 4*i] = *(short4v*)&hi[4*i];
                *(short4v*)&Al[row*36 + kseg + 4*i] = *(short4v*)&lo[4*i];
            }
        }
        __syncthreads();
        f32x16 acc;
        #pragma unroll
        for(int i=0;i<16;++i) acc[i]=0.f;
        #pragma unroll
        for(int s=0;s<2;++s){
            int abase = (wave*32 + c)*36 + s*16 + g*4;
            short8v ah, al;
            ((short4v*)&ah)[0] = *(short4v*)&Ah[abase];
            ((short4v*)&ah)[1] = *(short4v*)&Ah[abase + 8];
            ((short4v*)&al)[0] = *(short4v*)&Al[abase];
            ((short4v*)&al)[1] = *(short4v*)&Al[abase + 8];
            acc = __builtin_amdgcn_mfma_f32_32x32x16_bf16(ah, wh[s], acc, 0,0,0);
            acc = __builtin_amdgcn_mfma_f32_32x32x16_bf16(al, wh[s], acc, 0,0,0);
            acc = __builtin_amdgcn_mfma_f32_32x32x16_bf16(ah, wl[s], acc, 0,0,0);
        }
        #pragma unroll
        for(int r=0;r<16;++r){
            int rl = wave*32 + (r&3) + 8*(r>>2) + 4*g;
            int grow = rbase + rl;
            if(grow < U){
                float v = acc[r] + bc;
                v = v > 0.f ? v : 0.1f*v;
                x2b[grow*32 + c] = (unsigned short)f2bf_rne(v);
                s_acc += v; q_acc += v*v;
            }
        }
        __syncthreads();
    }
    s_acc += __shfl_xor(s_acc, 32);
    q_acc += __shfl_xor(q_acc, 32);
    if(l < 32){ red[wave][c] = s_acc; red[wave][32+c] = q_acc; }
    __syncthreads();
    if(tid < 64){
        float t = red[0][tid]+red[1][tid]+red[2][tid]+red[3][tid];
        atomicAdd(&stats[128+tid], t);
    }
}

// ---- P2 = lrelu(BN2(x2) @ W3 + b3) @ Wo1b  [U,64] bf16.  GEMM2 single-pass.
//      BN2 params computed per-block from raw sums (bnfin inlined). ----
__global__ void __launch_bounds__(256) k_ppm3(const unsigned short* __restrict__ x2b,
        const unsigned* __restrict__ Ucnt, const float* __restrict__ W3,
        const float* __restrict__ b3, const float* __restrict__ be2,
        const float* __restrict__ g2, const float* __restrict__ Wo1,
        unsigned short* __restrict__ P2, const float* __restrict__ stats){
    __shared__ __align__(16) short Ah[64*36];
    __shared__ __align__(16) short Al[64*36];
    __shared__ __align__(16) short Ih[64*68];
    __shared__ __align__(16) short Il[64*36];
    __shared__ float ash[32], bbsh[32];
    int tid = threadIdx.x;
    int wave = tid >> 6, l = tid & 63;
    int g = l >> 5, c = l & 31;
    int rowhalf = (wave >> 1) * 32, colhalf = (wave & 1) * 32;

    if(tid < 32){
        float n = (float)max(Ucnt[0], 1u);
        float mu = stats[128+tid]/n;
        float var = stats[160+tid]/n - mu*mu;
        float sc = g2[tid]*rsqrtf(var + EPSF);
        ash[tid]=sc; bbsh[tid]=be2[tid]-mu*sc;
    }
    if(tid >= 128){
        int t = tid - 128;
        int col = t >> 1, kseg = (t & 1) * 16;
        short hi[16], lo[16];
        #pragma unroll
        for(int j=0;j<16;++j){
            float v = W3[(kseg+j)*64 + col];
            short h = f2bf_rne(v);
            hi[j] = h; lo[j] = f2bf_rne(v - bf2f(h));
        }
        #pragma unroll
        for(int i=0;i<4;++i){
            *(short4v*)&Ih[col*36 + kseg + 4*i] = *(short4v*)&hi[4*i];
            *(short4v*)&Il[col*36 + kseg + 4*i] = *(short4v*)&lo[4*i];
        }
    }
    __syncthreads();
    short8v w3h[2], w3l[2];
    #pragma unroll
    for(int s=0;s<2;++s){
        int base = (colhalf + c)*36 + s*16 + g*4;
        ((short4v*)&w3h[s])[0] = *(short4v*)&Ih[base];
        ((short4v*)&w3h[s])[1] = *(short4v*)&Ih[base + 8];
        ((short4v*)&w3l[s])[0] = *(short4v*)&Il[base];
        ((short4v*)&w3l[s])[1] = *(short4v*)&Il[base + 8];
    }
    __syncthreads();
    // stage Wo1b^T (hi only), hoist
    {
        int col = tid >> 2, kseg = (tid & 3) * 16;
        short hi[16];
        #pragma unroll
        for(int j=0;j<16;++j) hi[j] = f2bf_rne(Wo1[4096 + (kseg+j)*64 + col]);
        #pragma unroll
        for(int i=0;i<4;++i)
            *(short4v*)&Ih[col*68 + kseg + 4*i] = *(short4v*)&hi[4*i];
    }
    __syncthreads();
    short8v w2h[4];
    #pragma unroll
    for(int s=0;s<4;++s){
        int base = (colhalf + c)*68 + s*16 + g*4;
        ((short4v*)&w2h[s])[0] = *(short4v*)&Ih[base];
        ((short4v*)&w2h[s])[1] = *(short4v*)&Ih[base + 8];
    }
    __syncthreads();

    int U = (int)Ucnt[0];
    float bc3 = b3[colhalf + c];

    const int NT = (N_PREV + 63) / 64;
    for(int tile = blockIdx.x; tile < NT; tile += gridDim.x){
        int rbase = tile * 64;
        if(rbase >= U) break;
        if(tid < 128){
            int row = tid >> 1, kseg = (tid & 1) * 16;
            int grow = rbase + row;
            float fv[16];
            if(grow < U){
                uint4 a0 = *(const uint4*)&x2b[grow*32 + kseg];
                uint4 a1 = *(const uint4*)&x2b[grow*32 + kseg + 8];
                unsigned wv[8] = {a0.x,a0.y,a0.z,a0.w,a1.x,a1.y,a1.z,a1.w};
                #pragma unroll
                for(int k=0;k<8;++k){
                    float lo = __uint_as_float(wv[k]<<16);
                    float hi = __uint_as_float(wv[k]&0xffff0000u);
                    fv[2*k]   = lo*ash[kseg+2*k]   + bbsh[kseg+2*k];
                    fv[2*k+1] = hi*ash[kseg+2*k+1] + bbsh[kseg+2*k+1];
                }
            } else {
                #pragma unroll
                for(int j=0;j<16;++j) fv[j]=0.f;
            }
            short hi[16], lo[16];
            #pragma unroll
            for(int j=0;j<16;++j){
                short h = f2bf_rne(fv[j]);
                hi[j] = h; lo[j] = f2bf_rne(fv[j] - bf2f(h));
            }
            #pragma unroll
            for(int i=0;i<4;++i){
                *(short4v*)&Ah[row*36 + kseg + 4*i] = *(short4v*)&hi[4*i];
                *(short4v*)&Al[row*36 + kseg + 4*i] = *(short4v*)&lo[4*i];
            }
        }
        __syncthreads();
        f32x16 acc;
        #pragma unroll
        for(int i=0;i<16;++i) acc[i]=0.f;
        #pragma unroll
        for(int s=0;s<2;++s){
            int abase = (rowhalf + c)*36 + s*16 + g*4;
            short8v ah, al;
            ((short4v*)&ah)[0] = *(short4v*)&Ah[abase];
            ((short4v*)&ah)[1] = *(short4v*)&Ah[abase + 8];
            ((short4v*)&al)[0] = *(short4v*)&Al[abase];
            ((short4v*)&al)[1] = *(short4v*)&Al[abase + 8];
            acc = __builtin_amdgcn_mfma_f32_32x32x16_bf16(ah, w3h[s], acc, 0,0,0);
            acc = __builtin_amdgcn_mfma_f32_32x32x16_bf16(al, w3h[s], acc, 0,0,0);
            acc = __builtin_amdgcn_mfma_f32_32x32x16_bf16(ah, w3l[s], acc, 0,0,0);
        }
        #pragma unroll
        for(int r=0;r<16;++r){
            int row = rowhalf + (r&3) + 8*(r>>2) + 4*g;
            float v = acc[r] + bc3;
            v = v > 0.f ? v : 0.1f*v;
            Ih[row*68 + colhalf + c] = f2bf_rne(v);
        }
        __syncthreads();
        f32x16 acc2;
        #pragma unroll
        for(int i=0;i<16;++i) acc2[i]=0.f;
        #pragma unroll
        for(int s=0;s<4;++s){
            int abase = (rowhalf + c)*68 + s*16 + g*4;
            short8v ah;
            ((short4v*)&ah)[0] = *(short4v*)&Ih[abase];
            ((short4v*)&ah)[1] = *(short4v*)&Ih[abase + 8];
            acc2 = __builtin_amdgcn_mfma_f32_32x32x16_bf16(ah, w2h[s], acc2, 0,0,0);
        }
        #pragma unroll
        for(int r=0;r<16;++r){
            int grow = rbase + rowhalf + (r&3) + 8*(r>>2) + 4*g;
            if(grow < U) P2[grow*64 + colhalf + c] = (unsigned short)f2bf_rne(acc2[r]);
        }
        __syncthreads();
    }
}

// ---- one wave per voxel (R9-verified gather, cross-voxel csr prefetch):
//      T[vox] = Σ lrelu(P1[j]+P2[h]+bo1) ----
__global__ void __launch_bounds__(256) k_vox(const unsigned* __restrict__ vstart,
        const int* __restrict__ csr_j, const int* __restrict__ csr_h,
        const unsigned short* __restrict__ P1, const unsigned short* __restrict__ P2,
        const float* __restrict__ bo1, float* __restrict__ T){
    int tid = threadIdx.x;
    int wib = tid>>6, lane = tid&63;
    float b1c = bo1[lane];
    int vox0 = (blockIdx.x*4 + wib)*4;
    // preload voxel 0's range + csr
    int s = (int)vstart[vox0];
    int e = (int)vstart[vox0+1];
    int jv = 0, hv = 0;
    {
        int n0 = min(e - s, 64);
        if(lane < n0){ jv = csr_j[s+lane]; hv = csr_h[s+lane]; }
    }
    for(int vq=0; vq<4; ++vq){
        int vox = vox0 + vq;
        int cs = s, ce = e, cjv = jv, chv = hv;
        if(vq < 3){
            // prefetch next voxel (vstart[vox+1] == current end)
            s = e;
            e = (int)vstart[vox+2];
            int n2 = min(e - s, 64);
            jv = 0; hv = 0;
            if(lane < n2){ jv = csr_j[s+lane]; hv = csr_h[s+lane]; }
        }
        float acc = 0.f;
        for(int i=cs; i<ce; i+=64){
            int n = min(ce-i, 64);
            int jj = cjv, hh = chv;
            if(i > cs){
                jj = 0; hh = 0;
                if(lane < n){ jj = csr_j[i+lane]; hh = csr_h[i+lane]; }
            }
            for(int q0=0; q0<n; q0+=8){
                float pa[8], pb[8];
                #pragma unroll
                for(int t=0;t<8;++t){
                    int qq = q0 + t;
                    qq = (qq < n) ? qq : q0;
                    int j = __shfl(jj, qq);
                    int h = __shfl(hh, qq);
                    pa[t] = bf2f((short)P1[(size_t)j*64 + lane]);
                    pb[t] = bf2f((short)P2[(size_t)h*64 + lane]);
                }
                #pragma unroll
                for(int t=0;t<8;++t){
                    if(q0 + t < n){
                        float g = pa[t] + pb[t] + b1c;
                        acc += (g>0.f) ? g : 0.1f*g;
                    }
                }
            }
        }
        T[(size_t)vox*64 + lane] = acc;
    }
}

// ---- out = (T @ Wo2)/max(cnt,1) + bo2*[cnt>0].  MFMA 3-pass (f32-grade). ----
__global__ void __launch_bounds__(256) k_wo2(const float* __restrict__ T,
        const unsigned* __restrict__ vstart, const float* __restrict__ Wo2,
        const float* __restrict__ bo2, float* __restrict__ out){
    __shared__ __align__(16) short Ah[64*68];
    __shared__ __align__(16) short Al[64*68];
    __shared__ float csh[64];
    int tid = threadIdx.x;
    int wave = tid >> 6, l = tid & 63;
    int g = l >> 5, c = l & 31;
    int rowhalf = (wave >> 1) * 32, colhalf = (wave & 1) * 32;

    // stage Wo2^T (hi/lo), hoist
    {
        int col = tid >> 2, kseg = (tid & 3) * 16;
        short hi[16], lo[16];
        #pragma unroll
        for(int j=0;j<16;++j){
            float v = Wo2[(kseg+j)*64 + col];
            short h = f2bf_rne(v);
            hi[j] = h; lo[j] = f2bf_rne(v - bf2f(h));
        }
        #pragma unroll
        for(int i=0;i<4;++i){
            *(short4v*)&Ah[col*68 + kseg + 4*i] = *(short4v*)&hi[4*i];
            *(short4v*)&Al[col*68 + kseg + 4*i] = *(short4v*)&lo[4*i];
        }
    }
    __syncthreads();
    short8v wh[4], wl[4];
    #pragma unroll
    for(int s=0;s<4;++s){
        int base = (colhalf + c)*68 + s*16 + g*4;
        ((short4v*)&wh[s])[0] = *(short4v*)&Ah[base];
        ((short4v*)&wh[s])[1] = *(short4v*)&Ah[base + 8];
        ((short4v*)&wl[s])[0] = *(short4v*)&Al[base];
        ((short4v*)&wl[s])[1] = *(short4v*)&Al[base + 8];
    }
    __syncthreads();

    float bo2c = bo2[colhalf + c];

    const int NT = NVOX / 64;    // 1024
    for(int tile = blockIdx.x; tile < NT; tile += gridDim.x){
        int rbase = tile * 64;
        // stage T tile hi/lo (all rows valid)
        {
            int row = tid >> 2, kseg = (tid & 3) * 16;
            const float4* fp = (const float4*)&T[(size_t)(rbase + row)*64 + kseg];
            float fv[16];
            *(float4*)&fv[0]  = fp[0];
            *(float4*)&fv[4]  = fp[1];
            *(float4*)&fv[8]  = fp[2];
            *(float4*)&fv[12] = fp[3];
            short hi[16], lo[16];
            #pragma unroll
            for(int j=0;j<16;++j){
                short h = f2bf_rne(fv[j]);
                hi[j] = h; lo[j] = f2bf_rne(fv[j] - bf2f(h));
            }
            #pragma unroll
            for(int i=0;i<4;++i){
                *(short4v*)&Ah[row*68 + kseg + 4*i] = *(short4v*)&hi[4*i];
                *(short4v*)&Al[row*68 + kseg + 4*i] = *(short4v*)&lo[4*i];
            }
        }
        if(tid < 64){
            int vox = rbase + tid;
            csh[tid] = (float)(vstart[vox+1] - vstart[vox]);
        }
        __syncthreads();
        f32x16 acc;
        #pragma unroll
        for(int i=0;i<16;++i) acc[i]=0.f;
        #pragma unroll
        for(int s=0;s<4;++s){
            int abase = (rowhalf + c)*68 + s*16 + g*4;
            short8v ah, al;
            ((short4v*)&ah)[0] = *(short4v*)&Ah[abase];
            ((short4v*)&ah)[1] = *(short4v*)&Ah[abase + 8];
            ((short4v*)&al)[0] = *(short4v*)&Al[abase];
            ((short4v*)&al)[1] = *(short4v*)&Al[abase + 8];
            acc = __builtin_amdgcn_mfma_f32_32x32x16_bf16(ah, wh[s], acc, 0,0,0);
            acc = __builtin_amdgcn_mfma_f32_32x32x16_bf16(al, wh[s], acc, 0,0,0);
            acc = __builtin_amdgcn_mfma_f32_32x32x16_bf16(ah, wl[s], acc, 0,0,0);
        }
        #pragma unroll
        for(int r=0;r<16;++r){
            int row = rowhalf + (r&3) + 8*(r>>2) + 4*g;
            float cv = csh[row];
            float rv = (cv > 0.f) ? 1.0f/cv : 0.f;
            float bz = (cv > 0.f) ? bo2c : 0.f;
            out[(size_t)(rbase + row)*64 + colhalf + c] = acc[r]*rv + bz;
        }
        __syncthreads();
    }
}

extern "C" void kernel_launch(void* const* d_in, const int* in_sizes, int n_in,
                              void* d_out, int out_size, void* d_ws, size_t ws_size,
                              hipStream_t stream) {
    if(ws_size < WS_NEEDED) return;

    const float* features = (const float*)d_in[0];
    const int*   coors    = (const int*)d_in[1];
    const int*   cif      = (const int*)d_in[2];
    const int*   scv      = (const int*)d_in[3];
    const float* W_in     = (const float*)d_in[4];
    const float* b_in     = (const float*)d_in[5];
    const float* W1       = (const float*)d_in[6];
    const float* b1       = (const float*)d_in[7];
    const float* g1       = (const float*)d_in[8];
    const float* be1      = (const float*)d_in[9];
    const float* W2       = (const float*)d_in[10];
    const float* b2       = (const float*)d_in[11];
    const float* g2       = (const float*)d_in[12];
    const float* be2      = (const float*)d_in[13];
    const float* W3       = (const float*)d_in[14];
    const float* b3       = (const float*)d_in[15];
    const float* Wo1      = (const float*)d_in[16];
    const float* bo1      = (const float*)d_in[17];
    const float* Wo2      = (const float*)d_in[18];
    const float* bo2      = (const float*)d_in[19];

    char* ws = (char*)d_ws;
    unsigned* bitmap = (unsigned*)(ws + OFF_BITMAP);
    float*    stats  = (float*)(ws + OFF_STATS);
    float*    cnt    = (float*)(ws + OFF_CNT);
    unsigned* vh     = (unsigned*)(ws + OFF_VH);
    unsigned short* yb = (unsigned short*)(ws + OFF_Y);
    float*    T      = (float*)(ws + OFF_T);        // aliases yb (dead after ppm2)
    unsigned short* P2 = (unsigned short*)(ws + OFF_P2);
    unsigned* pref   = (unsigned*)(ws + OFF_PREF);
    unsigned* bsum   = (unsigned*)(ws + OFF_BSUM);
    unsigned* boff   = (unsigned*)(ws + OFF_BOFF);
    unsigned* Ucnt   = (unsigned*)(ws + OFF_UCNT);
    int*      inv    = (int*)(ws + OFF_INV);
    unsigned short* P1 = (unsigned short*)(ws + OFF_P1);
    unsigned short* x2b = (unsigned short*)(ws + OFF_X2);
    int*      csr_j  = (int*)(ws + OFF_CSRJ);
    int*      csr_h  = (int*)(ws + OFF_CSRH);
    unsigned* vstart = (unsigned*)(ws + OFF_VSTART);
    unsigned* vnext  = (unsigned*)(ws + OFF_VNEXT);
    unsigned* vpart  = (unsigned*)(ws + OFF_VPART);
    unsigned* vbsum  = (unsigned*)(ws + OFF_VBSUM);
    short*    wfrag  = (short*)(ws + OFF_WFRAG);    // head of x2b; dead before ppm2 writes

    hipMemsetAsync(d_ws, 0, ZERO_BYTES, stream);

    k_wprep <<<1, 256, 0, stream>>>(W_in, Wo1, W1, wfrag);
    k_mark  <<<(N_FULL+255)/256, 256, 0, stream>>>(coors, scv, bitmap, vh);
    k_scanA <<<1024, 1024, 0, stream>>>(bitmap, pref, bsum);
    k_scanB <<<1, 1024, 0, stream>>>(bsum, boff, Ucnt);
    k_p1f   <<<2048, 256, 0, stream>>>(features, coors, bitmap, pref, boff,
                                       b_in, wfrag, P1, inv, cnt, yb);
    // CSR build (overwrites bitmap/pref regions — safe after k_p1f)
    k_vscanA<<<64, 1024, 0, stream>>>(vh, vpart, vbsum);
    k_vfix  <<<64, 1024, 0, stream>>>(vpart, vbsum, vstart, vnext);
    k_fill  <<<(N_FULL+255)/256, 256, 0, stream>>>(cif, scv, inv, vnext, csr_j, csr_h);
    // PPmodel chain (BN finalize inlined into ppm2/ppm3)
    k_bn1   <<<1024, 256, 0, stream>>>(yb, cnt, Ucnt, b1, stats);
    k_ppm2  <<<1024, 256, 0, stream>>>(yb, cnt, Ucnt, W2, b1, b2, be1, g1, x2b, stats);
    k_ppm3  <<<1024, 256, 0, stream>>>(x2b, Ucnt, W3, b3, be2, g2, Wo1, P2, stats);
    // output stage: gather accumulate -> T, then fused GEMM + mean
    k_vox   <<<NVOX/16, 256, 0, stream>>>(vstart, csr_j, csr_h, P1, P2, bo1, T);
    k_wo2   <<<256, 256, 0, stream>>>(T, vstart, Wo2, bo2, (float*)d_out);
}

// Round 17
// 269.058 us; speedup vs baseline: 1.0451x; 1.0451x over previous
//
#include <hip/hip_runtime.h>

#define N_PREV 250000
#define N_FULL 500000
#define NVOX   65536
#define NWORDS (1u<<20)          // bitmap words; keyspace < 2^25 bits
#define EPSF   1e-5f

typedef __attribute__((ext_vector_type(4)))  short short4v;
typedef __attribute__((ext_vector_type(8)))  short short8v;
typedef __attribute__((ext_vector_type(16))) float f32x16;

__device__ __forceinline__ float lrelu(float x){ return x > 0.0f ? x : 0.1f*x; }
__device__ __forceinline__ short f2bf_rne(float v){
    unsigned u = __float_as_uint(v);
    unsigned r = (u + 0x7fffu + ((u>>16)&1u)) >> 16;
    return (short)r;
}
__device__ __forceinline__ float bf2f(short s){
    return __uint_as_float(((unsigned)(unsigned short)s) << 16);
}

// ---------------- ws layout (bytes) ----------------
// zeroed prefix:
#define OFF_BITMAP   0ul            // u32[NWORDS] (aliased as csr_j/csr_h after k_p1f)
#define OFF_STATS    4194304ul      // f32[256]
#define OFF_CNT      4195328ul      // f32[N_PREV]
#define OFF_VH       5195328ul      // u32[NVOX]
#define OFF_Y        5457472ul      // bf16[N_PREV*32]  16 MB  (dead after ppm2; T aliases here)
#define ZERO_BYTES   21457472ul
// not zeroed:
#define OFF_T        5457472ul      // f32[NVOX*64] 16.78 MB (k_vox -> k_wo2; after yb dead)
#define OFF_P2       37457472ul     // bf16[N_PREV*64] 32 MB
#define OFF_PREF     69457472ul     // u32[NWORDS] (aliased as vstart/vnext/vpart/vbsum after p1f)
#define OFF_BSUM     73651776ul
#define OFF_BOFF     73655872ul
#define OFF_UCNT     73659968ul
#define OFF_INV      73660224ul     // i32[N_PREV]
#define OFF_P1       74660224ul     // bf16[N_PREV*64] 32 MB
#define OFF_X2       106660224ul    // bf16[N_PREV*32]  16 MB
#define WS_NEEDED    138660224ul
#define OFF_CSRJ     0ul
#define OFF_CSRH     2000000ul
#define OFF_VSTART   69457472ul
#define OFF_VNEXT    (OFF_VSTART+262400ul)
#define OFF_VPART    (OFF_VNEXT+262144ul)
#define OFF_VBSUM    (OFF_VPART+262144ul)

__device__ __forceinline__ int voxel_key(int4 c){
    return ((c.x*501 + (c.y>>1))*501 + (c.z>>1))*31 + (c.w>>1);
}

// ---- mark present keys + voxel histogram (fused; independent scatters) ----
__global__ void k_mark(const int* __restrict__ coors, const int* __restrict__ scv,
                       unsigned* __restrict__ bitmap, unsigned* __restrict__ vh){
    int i = blockIdx.x*256 + threadIdx.x;
    if(i < N_PREV){
        int4 c = ((const int4*)coors)[i];
        int key = voxel_key(c);
        atomicOr(&bitmap[key>>5], 1u<<(key&31));
    }
    if(i < N_FULL) atomicAdd(&vh[scv[i]], 1u);
}

__global__ void __launch_bounds__(1024) k_scanA(const unsigned* __restrict__ bitmap,
                                                unsigned* __restrict__ pref,
                                                unsigned* __restrict__ bsum){
    __shared__ unsigned sh[1024];
    int tid = threadIdx.x;
    int w = blockIdx.x*1024 + tid;
    unsigned p = __popc(bitmap[w]);
    sh[tid] = p; __syncthreads();
    for(int off=1; off<1024; off<<=1){
        unsigned v = (tid>=off) ? sh[tid-off] : 0u;
        __syncthreads();
        sh[tid] += v;
        __syncthreads();
    }
    pref[w] = sh[tid] - p;
    if(tid==1023) bsum[blockIdx.x] = sh[tid];
}

__global__ void __launch_bounds__(1024) k_scanB(const unsigned* __restrict__ bsum,
                                                unsigned* __restrict__ boff,
                                                unsigned* __restrict__ Ucnt){
    __shared__ unsigned sh[1024];
    int tid = threadIdx.x;
    unsigned p = bsum[tid];
    sh[tid] = p; __syncthreads();
    for(int off=1; off<1024; off<<=1){
        unsigned v = (tid>=off) ? sh[tid-off] : 0u;
        __syncthreads();
        sh[tid] += v;
        __syncthreads();
    }
    boff[tid] = sh[tid] - p;
    if(tid==1023) Ucnt[0] = sh[tid];
}

// ---- CSR build over scale voxels ----
__global__ void __launch_bounds__(1024) k_vscanA(const unsigned* __restrict__ vh,
                                                 unsigned* __restrict__ vpart,
                                                 unsigned* __restrict__ vbsum){
    __shared__ unsigned sh[1024];
    int tid = threadIdx.x;
    int w = blockIdx.x*1024 + tid;
    unsigned p = vh[w];
    sh[tid] = p; __syncthreads();
    for(int off=1; off<1024; off<<=1){
        unsigned v = (tid>=off) ? sh[tid-off] : 0u;
        __syncthreads();
        sh[tid] += v;
        __syncthreads();
    }
    vpart[w] = sh[tid] - p;
    if(tid==1023) vbsum[blockIdx.x] = sh[tid];
}

// vscanB folded in: wave 0 redundantly scans the 64 block sums
__global__ void __launch_bounds__(1024) k_vfix(const unsigned* __restrict__ vpart,
                                               const unsigned* __restrict__ vbsum,
                                               unsigned* __restrict__ vstart,
                                               unsigned* __restrict__ vnext){
    __shared__ unsigned bo[64];
    int tid = threadIdx.x;
    if(tid < 64){
        unsigned v = vbsum[tid], orig = v;
        for(int off=1; off<64; off<<=1){
            unsigned o = __shfl_up(v, off);
            if(tid>=off) v += o;
        }
        bo[tid] = v - orig;   // exclusive
    }
    __syncthreads();
    int w = blockIdx.x*1024 + tid;
    unsigned s = vpart[w] + bo[w>>10];
    vstart[w] = s; vnext[w] = s;
    if(w == NVOX-1) vstart[NVOX] = N_FULL;
}

__global__ void k_fill(const int* __restrict__ cif, const int* __restrict__ scv,
                       const int* __restrict__ inv, unsigned* __restrict__ vnext,
                       int* __restrict__ csr_j, int* __restrict__ csr_h){
    int p = blockIdx.x*256 + threadIdx.x;
    if(p >= N_FULL) return;
    int jp = cif[p];
    unsigned pos = atomicAdd(&vnext[scv[p]], 1u);
    csr_j[pos] = jp;
    csr_h[pos] = inv[jp];
}

// ---- fused: P1 = lrelu(F@Win+b)@Wo1a (bf16 out, single-pass GEMM2);
//      Y = F@W1 3-pass, pk bf16 atomic scatter; rank/inv/cnt inline. ----
__global__ void __launch_bounds__(256) k_p1f(const float* __restrict__ feat,
        const int* __restrict__ coors, const unsigned* __restrict__ bitmap,
        const unsigned* __restrict__ pref, const unsigned* __restrict__ boff,
        const float* __restrict__ Win, const float* __restrict__ bin,
        const float* __restrict__ Wo1, const float* __restrict__ W1,
        unsigned short* __restrict__ P1, int* __restrict__ inv,
        float* __restrict__ cnt, unsigned short* __restrict__ yb){
    __shared__ __align__(16) short Ah[64*68];
    __shared__ __align__(16) short Al[64*68];
    __shared__ float ysh[64][33];
    __shared__ int rksh[64];
    int tid = threadIdx.x;
    int wave = tid >> 6, l = tid & 63;
    int g = l >> 5, c = l & 31;
    int rowhalf = (wave >> 1) * 32, colhalf = (wave & 1) * 32;

    // stage Win^T (hi/lo), hoist
    {
        int col = tid >> 2, kseg = (tid & 3) * 16;
        short hi[16], lo[16];
        #pragma unroll
        for(int j=0;j<16;++j){
            float v = Win[(kseg+j)*64 + col];
            short h = f2bf_rne(v);
            hi[j] = h; lo[j] = f2bf_rne(v - bf2f(h));
        }
        #pragma unroll
        for(int i=0;i<4;++i){
            *(short4v*)&Ah[col*68 + kseg + 4*i] = *(short4v*)&hi[4*i];
            *(short4v*)&Al[col*68 + kseg + 4*i] = *(short4v*)&lo[4*i];
        }
    }
    __syncthreads();
    short8v w1h[4], w1l[4];
    #pragma unroll
    for(int s=0;s<4;++s){
        int base = (colhalf + c)*68 + s*16 + g*4;
        ((short4v*)&w1h[s])[0] = *(short4v*)&Ah[base];
        ((short4v*)&w1h[s])[1] = *(short4v*)&Ah[base + 8];
        ((short4v*)&w1l[s])[0] = *(short4v*)&Al[base];
        ((short4v*)&w1l[s])[1] = *(short4v*)&Al[base + 8];
    }
    __syncthreads();
    // stage Wo1a^T (hi only), hoist
    {
        int col = tid >> 2, kseg = (tid & 3) * 16;
        short hi[16];
        #pragma unroll
        for(int j=0;j<16;++j) hi[j] = f2bf_rne(Wo1[(kseg+j)*64 + col]);
        #pragma unroll
        for(int i=0;i<4;++i)
            *(short4v*)&Ah[col*68 + kseg + 4*i] = *(short4v*)&hi[4*i];
    }
    __syncthreads();
    short8v w2h[4];
    #pragma unroll
    for(int s=0;s<4;++s){
        int base = (colhalf + c)*68 + s*16 + g*4;
        ((short4v*)&w2h[s])[0] = *(short4v*)&Ah[base];
        ((short4v*)&w2h[s])[1] = *(short4v*)&Ah[base + 8];
    }
    __syncthreads();
    // stage W1^T [32 col][64 k] (hi/lo), hoist
    if(tid < 128){
        int col = tid >> 2, kseg = (tid & 3) * 16;
        short hi[16], lo[16];
        #pragma unroll
        for(int j=0;j<16;++j){
            float v = W1[(kseg+j)*32 + col];
            short h = f2bf_rne(v);
            hi[j] = h; lo[j] = f2bf_rne(v - bf2f(h));
        }
        #pragma unroll
        for(int i=0;i<4;++i){
            *(short4v*)&Ah[col*68 + kseg + 4*i] = *(short4v*)&hi[4*i];
            *(short4v*)&Al[col*68 + kseg + 4*i] = *(short4v*)&lo[4*i];
        }
    }
    __syncthreads();
    short8v w0h[4], w0l[4];
    #pragma unroll
    for(int s=0;s<4;++s){
        int base = c*68 + s*16 + g*4;
        ((short4v*)&w0h[s])[0] = *(short4v*)&Ah[base];
        ((short4v*)&w0h[s])[1] = *(short4v*)&Ah[base + 8];
        ((short4v*)&w0l[s])[0] = *(short4v*)&Al[base];
        ((short4v*)&w0l[s])[1] = *(short4v*)&Al[base + 8];
    }
    __syncthreads();

    float bc1 = bin[colhalf + c];

    const int NT = (N_PREV + 63) / 64;
    for(int tile = blockIdx.x; tile < NT; tile += gridDim.x){
        int rbase = tile * 64;
        // stage F tile hi/lo
        {
            int row = tid >> 2, kseg = (tid & 3) * 16;
            int grow = rbase + row;
            float fv[16];
            if(grow < N_PREV){
                const float4* fp = (const float4*)&feat[grow*64 + kseg];
                *(float4*)&fv[0]  = fp[0];
                *(float4*)&fv[4]  = fp[1];
                *(float4*)&fv[8]  = fp[2];
                *(float4*)&fv[12] = fp[3];
            } else {
                #pragma unroll
                for(int j=0;j<16;++j) fv[j]=0.f;
            }
            short hi[16], lo[16];
            #pragma unroll
            for(int j=0;j<16;++j){
                short h = f2bf_rne(fv[j]);
                hi[j] = h; lo[j] = f2bf_rne(fv[j] - bf2f(h));
            }
            #pragma unroll
            for(int i=0;i<4;++i){
                *(short4v*)&Ah[row*68 + kseg + 4*i] = *(short4v*)&hi[4*i];
                *(short4v*)&Al[row*68 + kseg + 4*i] = *(short4v*)&lo[4*i];
            }
        }
        // ranks for this tile's rows
        if(tid < 64){
            int grow = rbase + tid;
            if(grow < N_PREV){
                int4 c4 = ((const int4*)coors)[grow];
                int key = voxel_key(c4);
                int w = key>>5, b = key&31;
                int rank = (int)(boff[w>>10] + pref[w]) + __popc(bitmap[w] & ((1u<<b)-1u));
                rksh[tid] = rank;
                inv[grow] = rank;
                atomicAdd(&cnt[rank], 1.0f);
            } else rksh[tid] = -1;
        }
        __syncthreads();
        // GEMM1: I = lrelu(F@Win + b)  (3-pass, all waves)
        f32x16 acc;
        #pragma unroll
        for(int i=0;i<16;++i) acc[i]=0.f;
        #pragma unroll
        for(int s=0;s<4;++s){
            int abase = (rowhalf + c)*68 + s*16 + g*4;
            short8v ah, al;
            ((short4v*)&ah)[0] = *(short4v*)&Ah[abase];
            ((short4v*)&ah)[1] = *(short4v*)&Ah[abase + 8];
            ((short4v*)&al)[0] = *(short4v*)&Al[abase];
            ((short4v*)&al)[1] = *(short4v*)&Al[abase + 8];
            acc = __builtin_amdgcn_mfma_f32_32x32x16_bf16(ah, w1h[s], acc, 0,0,0);
            acc = __builtin_amdgcn_mfma_f32_32x32x16_bf16(al, w1h[s], acc, 0,0,0);
            acc = __builtin_amdgcn_mfma_f32_32x32x16_bf16(ah, w1l[s], acc, 0,0,0);
        }
        // GEMM0: Y = F@W1  (3-pass, waves 0/1)
        f32x16 accY;
        #pragma unroll
        for(int i=0;i<16;++i) accY[i]=0.f;
        if(wave < 2){
            #pragma unroll
            for(int s=0;s<4;++s){
                int abase = (wave*32 + c)*68 + s*16 + g*4;
                short8v ah, al;
                ((short4v*)&ah)[0] = *(short4v*)&Ah[abase];
                ((short4v*)&ah)[1] = *(short4v*)&Ah[abase + 8];
                ((short4v*)&al)[0] = *(short4v*)&Al[abase];
                ((short4v*)&al)[1] = *(short4v*)&Al[abase + 8];
                accY = __builtin_amdgcn_mfma_f32_32x32x16_bf16(ah, w0h[s], accY, 0,0,0);
                accY = __builtin_amdgcn_mfma_f32_32x32x16_bf16(al, w0h[s], accY, 0,0,0);
                accY = __builtin_amdgcn_mfma_f32_32x32x16_bf16(ah, w0l[s], accY, 0,0,0);
            }
        }
        __syncthreads();
        // epilogue: I-hi -> Ah; Y -> ysh
        #pragma unroll
        for(int r=0;r<16;++r){
            int row = rowhalf + (r&3) + 8*(r>>2) + 4*g;
            float v = acc[r] + bc1;
            v = v > 0.f ? v : 0.1f*v;
            Ah[row*68 + colhalf + c] = f2bf_rne(v);
        }
        if(wave < 2){
            #pragma unroll
            for(int r=0;r<16;++r){
                int row = wave*32 + (r&3) + 8*(r>>2) + 4*g;
                ysh[row][c] = accY[r];
            }
        }
        __syncthreads();
        // GEMM2: P1 = I @ Wo1a  (single-pass; P1 stored bf16 anyway)
        f32x16 acc2;
        #pragma unroll
        for(int i=0;i<16;++i) acc2[i]=0.f;
        #pragma unroll
        for(int s=0;s<4;++s){
            int abase = (rowhalf + c)*68 + s*16 + g*4;
            short8v ah;
            ((short4v*)&ah)[0] = *(short4v*)&Ah[abase];
            ((short4v*)&ah)[1] = *(short4v*)&Ah[abase + 8];
            acc2 = __builtin_amdgcn_mfma_f32_32x32x16_bf16(ah, w2h[s], acc2, 0,0,0);
        }
        #pragma unroll
        for(int r=0;r<16;++r){
            int grow = rbase + rowhalf + (r&3) + 8*(r>>2) + 4*g;
            if(grow < N_PREV) P1[grow*64 + colhalf + c] = (unsigned short)f2bf_rne(acc2[r]);
        }
        // scatter Y tile into yb by rank (packed bf16 atomics: 2 channels/op)
        #pragma unroll
        for(int q=0;q<4;++q){
            int e = q*256 + tid;          // 64 rows x 16 pairs
            int row = e >> 4, pr = e & 15;
            int rk = rksh[row];
            if(rk >= 0){
                unsigned h0 = (unsigned)(unsigned short)f2bf_rne(ysh[row][2*pr]);
                unsigned h1 = (unsigned)(unsigned short)f2bf_rne(ysh[row][2*pr+1]);
                unsigned pk = h0 | (h1 << 16);
                unsigned short* addr = yb + (size_t)rk*32 + 2*pr;
                asm volatile("global_atomic_pk_add_bf16 %0, %1, off"
                             :: "v"(addr), "v"(pk) : "memory");
            }
        }
        __syncthreads();
    }
}

// ---- BN1 stats over x1 = lrelu(y/cnt + b1)  (stats only; y is bf16) ----
__global__ void __launch_bounds__(256) k_bn1(const unsigned short* __restrict__ yb,
        const float* __restrict__ cnt, const unsigned* __restrict__ Ucnt,
        const float* __restrict__ b1, float* __restrict__ stats){
    __shared__ float sst[32], qst[32];
    int tid = threadIdx.x;
    if(tid < 32){ sst[tid]=0.f; qst[tid]=0.f; }
    __syncthreads();
    int U = (int)Ucnt[0];
    int total = U*4;                 // uint4 (8 bf16) per element
    int c8 = (tid&3)*8;
    float bb[8];
    #pragma unroll
    for(int j=0;j<8;++j) bb[j] = b1[c8+j];
    float s[8], q[8];
    #pragma unroll
    for(int j=0;j<8;++j){ s[j]=0.f; q[j]=0.f; }
    for(int e = blockIdx.x*256 + tid; e < total; e += gridDim.x*256){
        int row = e >> 2;
        float rv = 1.0f/cnt[row];
        uint4 a = ((const uint4*)yb)[e];
        unsigned wv[4] = {a.x,a.y,a.z,a.w};
        #pragma unroll
        for(int k=0;k<4;++k){
            float lo = __uint_as_float(wv[k]<<16);
            float hi = __uint_as_float(wv[k]&0xffff0000u);
            float v0 = lrelu(lo*rv + bb[2*k]);
            float v1 = lrelu(hi*rv + bb[2*k+1]);
            s[2*k]+=v0; q[2*k]+=v0*v0;
            s[2*k+1]+=v1; q[2*k+1]+=v1*v1;
        }
    }
    #pragma unroll
    for(int j=0;j<8;++j){ atomicAdd(&sst[c8+j], s[j]); atomicAdd(&qst[c8+j], q[j]); }
    __syncthreads();
    if(tid < 32){ atomicAdd(&stats[tid], sst[tid]); atomicAdd(&stats[32+tid], qst[tid]); }
}

// ---- x2 = lrelu(BN1(lrelu(y/cnt+b1)) @ W2 + b2) (bf16 out), BN2 stats.
//      BN1 params computed per-block from raw sums (bnfin inlined). ----
__global__ void __launch_bounds__(256) k_ppm2(const unsigned short* __restrict__ yb,
        const float* __restrict__ cnt, const unsigned* __restrict__ Ucnt,
        const float* __restrict__ W2, const float* __restrict__ b1i,
        const float* __restrict__ b2, const float* __restrict__ be1,
        const float* __restrict__ g1, unsigned short* __restrict__ x2b,
        float* __restrict__ stats){
    __shared__ __align__(16) short Ah[128*36];
    __shared__ __align__(16) short Al[128*36];
    __shared__ float ash[32], bbsh[32], b1sh[32];
    __shared__ float red[4][64];
    int tid = threadIdx.x;
    int wave = tid >> 6, l = tid & 63;
    int g = l >> 5, c = l & 31;

    if(tid < 32){
        float n = (float)max(Ucnt[0], 1u);
        float mu = stats[tid]/n;
        float var = stats[32+tid]/n - mu*mu;
        float sc = g1[tid]*rsqrtf(var + EPSF);
        ash[tid]=sc; bbsh[tid]=be1[tid]-mu*sc;
        b1sh[tid]=b1i[tid];
    }
    if(tid >= 64 && tid < 128){
        int t = tid - 64;
        int col = t >> 1, kseg = (t & 1) * 16;
        short hi[16], lo[16];
        #pragma unroll
        for(int j=0;j<16;++j){
            float v = W2[(kseg+j)*32 + col];
            short h = f2bf_rne(v);
            hi[j] = h; lo[j] = f2bf_rne(v - bf2f(h));
        }
        #pragma unroll
        for(int i=0;i<4;++i){
            *(short4v*)&Ah[col*36 + kseg + 4*i] = *(short4v*)&hi[4*i];
            *(short4v*)&Al[col*36 + kseg + 4*i] = *(short4v*)&lo[4*i];
        }
    }
    __syncthreads();
    short8v wh[2], wl[2];
    #pragma unroll
    for(int s=0;s<2;++s){
        int base = c*36 + s*16 + g*4;
        ((short4v*)&wh[s])[0] = *(short4v*)&Ah[base];
        ((short4v*)&wh[s])[1] = *(short4v*)&Ah[base + 8];
        ((short4v*)&wl[s])[0] = *(short4v*)&Al[base];
        ((short4v*)&wl[s])[1] = *(short4v*)&Al[base + 8];
    }
    __syncthreads();

    int U = (int)Ucnt[0];
    float bc = b2[c];
    float s_acc = 0.f, q_acc = 0.f;

    const int NT = (N_PREV + 127) / 128;
    for(int tile = blockIdx.x; tile < NT; tile += gridDim.x){
        int rbase = tile * 128;
        if(rbase >= U) break;
        {
            int row = tid >> 1, kseg = (tid & 1) * 16;
            int grow = rbase + row;
            float fv[16];
            if(grow < U){
                float rv = 1.0f/cnt[grow];
                uint4 a0 = *(const uint4*)&yb[grow*32 + kseg];
                uint4 a1 = *(const uint4*)&yb[grow*32 + kseg + 8];
                unsigned wv[8] = {a0.x,a0.y,a0.z,a0.w,a1.x,a1.y,a1.z,a1.w};
                #pragma unroll
                for(int k=0;k<8;++k){
                    float lo = __uint_as_float(wv[k]<<16);
                    float hi = __uint_as_float(wv[k]&0xffff0000u);
                    float v0 = lrelu(lo*rv + b1sh[kseg+2*k]);
                    float v1 = lrelu(hi*rv + b1sh[kseg+2*k+1]);
                    fv[2*k]   = v0*ash[kseg+2*k]   + bbsh[kseg+2*k];
                    fv[2*k+1] = v1*ash[kseg+2*k+1] + bbsh[kseg+2*k+1];
                }
            } else {
                #pragma unroll
                for(int j=0;j<16;++j) fv[j]=0.f;
            }
            short hi[16], lo[16];
            #pragma unroll
            for(int j=0;j<16;++j){
                short h = f2bf_rne(fv[j]);
                hi[j] = h; lo[j] = f2bf_rne(fv[j] - bf2f(h));
            }
            #pragma unroll
            for(int i=0;i<4;++i){
                *(short4v*)&Ah[row*36 + kseg + 4*i] = *(short4v*)&hi[4*i];
                *(short4v*)&Al[row*36 + kseg + 4*i] = *(short4v*)&lo[4*i];
            }
        }
        __syncthreads();
        f32x16 acc;
        #pragma unroll
        for(int i=0;i<16;++i) acc[i]=0.f;
        #pragma unroll
        for(int s=0;s<2;++s){
            int abase = (wave*32 + c)*36 + s*16 + g*4;
            short8v ah, al;
            ((short4v*)&ah)[0] = *(short4v*)&Ah[abase];
            ((short4v*)&ah)[1] = *(short4v*)&Ah[abase + 8];
            ((short4v*)&al)[0] = *(short4v*)&Al[abase];
            ((short4v*)&al)[1] = *(short4v*)&Al[abase + 8];
            acc = __builtin_amdgcn_mfma_f32_32x32x16_bf16(ah, wh[s], acc, 0,0,0);
            acc = __builtin_amdgcn_mfma_f32_32x32x16_bf16(al, wh[s], acc, 0,0,0);
            acc = __builtin_amdgcn_mfma_f32_32x32x16_bf16(ah, wl[s], acc, 0,0,0);
        }
        #pragma unroll
        for(int r=0;r<16;++r){
            int rl = wave*32 + (r&3) + 8*(r>>2) + 4*g;
            int grow = rbase + rl;
            if(grow < U){
                float v = acc[r] + bc;
                v = v > 0.f ? v : 0.1f*v;
                x2b[grow*32 + c] = (unsigned short)f2bf_rne(v);
                s_acc += v; q_acc += v*v;
            }
        }
        __syncthreads();
    }
    s_acc += __shfl_xor(s_acc, 32);
    q_acc += __shfl_xor(q_acc, 32);
    if(l < 32){ red[wave][c] = s_acc; red[wave][32+c] = q_acc; }
    __syncthreads();
    if(tid < 64){
        float t = red[0][tid]+red[1][tid]+red[2][tid]+red[3][tid];
        atomicAdd(&stats[128+tid], t);
    }
}

// ---- P2 = lrelu(BN2(x2) @ W3 + b3) @ Wo1b  [U,64] bf16.  GEMM2 single-pass.
//      BN2 params computed per-block from raw sums (bnfin inlined). ----
__global__ void __launch_bounds__(256) k_ppm3(const unsigned short* __restrict__ x2b,
        const unsigned* __restrict__ Ucnt, const float* __restrict__ W3,
        const float* __restrict__ b3, const float* __restrict__ be2,
        const float* __restrict__ g2, const float* __restrict__ Wo1,
        unsigned short* __restrict__ P2, const float* __restrict__ stats){
    __shared__ __align__(16) short Ah[64*36];
    __shared__ __align__(16) short Al[64*36];
    __shared__ __align__(16) short Ih[64*68];
    __shared__ __align__(16) short Il[64*36];
    __shared__ float ash[32], bbsh[32];
    int tid = threadIdx.x;
    int wave = tid >> 6, l = tid & 63;
    int g = l >> 5, c = l & 31;
    int rowhalf = (wave >> 1) * 32, colhalf = (wave & 1) * 32;

    if(tid < 32){
        float n = (float)max(Ucnt[0], 1u);
        float mu = stats[128+tid]/n;
        float var = stats[160+tid]/n - mu*mu;
        float sc = g2[tid]*rsqrtf(var + EPSF);
        ash[tid]=sc; bbsh[tid]=be2[tid]-mu*sc;
    }
    if(tid >= 128){
        int t = tid - 128;
        int col = t >> 1, kseg = (t & 1) * 16;
        short hi[16], lo[16];
        #pragma unroll
        for(int j=0;j<16;++j){
            float v = W3[(kseg+j)*64 + col];
            short h = f2bf_rne(v);
            hi[j] = h; lo[j] = f2bf_rne(v - bf2f(h));
        }
        #pragma unroll
        for(int i=0;i<4;++i){
            *(short4v*)&Ih[col*36 + kseg + 4*i] = *(short4v*)&hi[4*i];
            *(short4v*)&Il[col*36 + kseg + 4*i] = *(short4v*)&lo[4*i];
        }
    }
    __syncthreads();
    short8v w3h[2], w3l[2];
    #pragma unroll
    for(int s=0;s<2;++s){
        int base = (colhalf + c)*36 + s*16 + g*4;
        ((short4v*)&w3h[s])[0] = *(short4v*)&Ih[base];
        ((short4v*)&w3h[s])[1] = *(short4v*)&Ih[base + 8];
        ((short4v*)&w3l[s])[0] = *(short4v*)&Il[base];
        ((short4v*)&w3l[s])[1] = *(short4v*)&Il[base + 8];
    }
    __syncthreads();
    // stage Wo1b^T (hi only), hoist
    {
        int col = tid >> 2, kseg = (tid & 3) * 16;
        short hi[16];
        #pragma unroll
        for(int j=0;j<16;++j) hi[j] = f2bf_rne(Wo1[4096 + (kseg+j)*64 + col]);
        #pragma unroll
        for(int i=0;i<4;++i)
            *(short4v*)&Ih[col*68 + kseg + 4*i] = *(short4v*)&hi[4*i];
    }
    __syncthreads();
    short8v w2h[4];
    #pragma unroll
    for(int s=0;s<4;++s){
        int base = (colhalf + c)*68 + s*16 + g*4;
        ((short4v*)&w2h[s])[0] = *(short4v*)&Ih[base];
        ((short4v*)&w2h[s])[1] = *(short4v*)&Ih[base + 8];
    }
    __syncthreads();

    int U = (int)Ucnt[0];
    float bc3 = b3[colhalf + c];

    const int NT = (N_PREV + 63) / 64;
    for(int tile = blockIdx.x; tile < NT; tile += gridDim.x){
        int rbase = tile * 64;
        if(rbase >= U) break;
        if(tid < 128){
            int row = tid >> 1, kseg = (tid & 1) * 16;
            int grow = rbase + row;
            float fv[16];
            if(grow < U){
                uint4 a0 = *(const uint4*)&x2b[grow*32 + kseg];
                uint4 a1 = *(const uint4*)&x2b[grow*32 + kseg + 8];
                unsigned wv[8] = {a0.x,a0.y,a0.z,a0.w,a1.x,a1.y,a1.z,a1.w};
                #pragma unroll
                for(int k=0;k<8;++k){
                    float lo = __uint_as_float(wv[k]<<16);
                    float hi = __uint_as_float(wv[k]&0xffff0000u);
                    fv[2*k]   = lo*ash[kseg+2*k]   + bbsh[kseg+2*k];
                    fv[2*k+1] = hi*ash[kseg+2*k+1] + bbsh[kseg+2*k+1];
                }
            } else {
                #pragma unroll
                for(int j=0;j<16;++j) fv[j]=0.f;
            }
            short hi[16], lo[16];
            #pragma unroll
            for(int j=0;j<16;++j){
                short h = f2bf_rne(fv[j]);
                hi[j] = h; lo[j] = f2bf_rne(fv[j] - bf2f(h));
            }
            #pragma unroll
            for(int i=0;i<4;++i){
                *(short4v*)&Ah[row*36 + kseg + 4*i] = *(short4v*)&hi[4*i];
                *(short4v*)&Al[row*36 + kseg + 4*i] = *(short4v*)&lo[4*i];
            }
        }
        __syncthreads();
        f32x16 acc;
        #pragma unroll
        for(int i=0;i<16;++i) acc[i]=0.f;
        #pragma unroll
        for(int s=0;s<2;++s){
            int abase = (rowhalf + c)*36 + s*16 + g*4;
            short8v ah, al;
            ((short4v*)&ah)[0] = *(short4v*)&Ah[abase];
            ((short4v*)&ah)[1] = *(short4v*)&Ah[abase + 8];
            ((short4v*)&al)[0] = *(short4v*)&Al[abase];
            ((short4v*)&al)[1] = *(short4v*)&Al[abase + 8];
            acc = __builtin_amdgcn_mfma_f32_32x32x16_bf16(ah, w3h[s], acc, 0,0,0);
            acc = __builtin_amdgcn_mfma_f32_32x32x16_bf16(al, w3h[s], acc, 0,0,0);
            acc = __builtin_amdgcn_mfma_f32_32x32x16_bf16(ah, w3l[s], acc, 0,0,0);
        }
        #pragma unroll
        for(int r=0;r<16;++r){
            int row = rowhalf + (r&3) + 8*(r>>2) + 4*g;
            float v = acc[r] + bc3;
            v = v > 0.f ? v : 0.1f*v;
            Ih[row*68 + colhalf + c] = f2bf_rne(v);
        }
        __syncthreads();
        f32x16 acc2;
        #pragma unroll
        for(int i=0;i<16;++i) acc2[i]=0.f;
        #pragma unroll
        for(int s=0;s<4;++s){
            int abase = (rowhalf + c)*68 + s*16 + g*4;
            short8v ah;
            ((short4v*)&ah)[0] = *(short4v*)&Ih[abase];
            ((short4v*)&ah)[1] = *(short4v*)&Ih[abase + 8];
            acc2 = __builtin_amdgcn_mfma_f32_32x32x16_bf16(ah, w2h[s], acc2, 0,0,0);
        }
        #pragma unroll
        for(int r=0;r<16;++r){
            int grow = rbase + rowhalf + (r&3) + 8*(r>>2) + 4*g;
            if(grow < U) P2[grow*64 + colhalf + c] = (unsigned short)f2bf_rne(acc2[r]);
        }
        __syncthreads();
    }
}

// ---- one wave per voxel (R9-verified gather, cross-voxel csr prefetch):
//      T[vox] = Σ lrelu(P1[j]+P2[h]+bo1) ----
__global__ void __launch_bounds__(256) k_vox(const unsigned* __restrict__ vstart,
        const int* __restrict__ csr_j, const int* __restrict__ csr_h,
        const unsigned short* __restrict__ P1, const unsigned short* __restrict__ P2,
        const float* __restrict__ bo1, float* __restrict__ T){
    int tid = threadIdx.x;
    int wib = tid>>6, lane = tid&63;
    float b1c = bo1[lane];
    int vox0 = (blockIdx.x*4 + wib)*4;
    // preload voxel 0's range + csr
    int s = (int)vstart[vox0];
    int e = (int)vstart[vox0+1];
    int jv = 0, hv = 0;
    {
        int n0 = min(e - s, 64);
        if(lane < n0){ jv = csr_j[s+lane]; hv = csr_h[s+lane]; }
    }
    for(int vq=0; vq<4; ++vq){
        int vox = vox0 + vq;
        int cs = s, ce = e, cjv = jv, chv = hv;
        if(vq < 3){
            // prefetch next voxel (vstart[vox+1] == current end)
            s = e;
            e = (int)vstart[vox+2];
            int n2 = min(e - s, 64);
            jv = 0; hv = 0;
            if(lane < n2){ jv = csr_j[s+lane]; hv = csr_h[s+lane]; }
        }
        float acc = 0.f;
        for(int i=cs; i<ce; i+=64){
            int n = min(ce-i, 64);
            int jj = cjv, hh = chv;
            if(i > cs){
                jj = 0; hh = 0;
                if(lane < n){ jj = csr_j[i+lane]; hh = csr_h[i+lane]; }
            }
            for(int q0=0; q0<n; q0+=8){
                float pa[8], pb[8];
                #pragma unroll
                for(int t=0;t<8;++t){
                    int qq = q0 + t;
                    qq = (qq < n) ? qq : q0;
                    int j = __shfl(jj, qq);
                    int h = __shfl(hh, qq);
                    pa[t] = bf2f((short)P1[(size_t)j*64 + lane]);
                    pb[t] = bf2f((short)P2[(size_t)h*64 + lane]);
                }
                #pragma unroll
                for(int t=0;t<8;++t){
                    if(q0 + t < n){
                        float g = pa[t] + pb[t] + b1c;
                        acc += (g>0.f) ? g : 0.1f*g;
                    }
                }
            }
        }
        T[(size_t)vox*64 + lane] = acc;
    }
}

// ---- out = (T @ Wo2)/max(cnt,1) + bo2*[cnt>0].  MFMA 3-pass (f32-grade). ----
__global__ void __launch_bounds__(256) k_wo2(const float* __restrict__ T,
        const unsigned* __restrict__ vstart, const float* __restrict__ Wo2,
        const float* __restrict__ bo2, float* __restrict__ out){
    __shared__ __align__(16) short Ah[64*68];
    __shared__ __align__(16) short Al[64*68];
    __shared__ float csh[64];
    int tid = threadIdx.x;
    int wave = tid >> 6, l = tid & 63;
    int g = l >> 5, c = l & 31;
    int rowhalf = (wave >> 1) * 32, colhalf = (wave & 1) * 32;

    // stage Wo2^T (hi/lo), hoist
    {
        int col = tid >> 2, kseg = (tid & 3) * 16;
        short hi[16], lo[16];
        #pragma unroll
        for(int j=0;j<16;++j){
            float v = Wo2[(kseg+j)*64 + col];
            short h = f2bf_rne(v);
            hi[j] = h; lo[j] = f2bf_rne(v - bf2f(h));
        }
        #pragma unroll
        for(int i=0;i<4;++i){
            *(short4v*)&Ah[col*68 + kseg + 4*i] = *(short4v*)&hi[4*i];
            *(short4v*)&Al[col*68 + kseg + 4*i] = *(short4v*)&lo[4*i];
        }
    }
    __syncthreads();
    short8v wh[4], wl[4];
    #pragma unroll
    for(int s=0;s<4;++s){
        int base = (colhalf + c)*68 + s*16 + g*4;
        ((short4v*)&wh[s])[0] = *(short4v*)&Ah[base];
        ((short4v*)&wh[s])[1] = *(short4v*)&Ah[base + 8];
        ((short4v*)&wl[s])[0] = *(short4v*)&Al[base];
        ((short4v*)&wl[s])[1] = *(short4v*)&Al[base + 8];
    }
    __syncthreads();

    float bo2c = bo2[colhalf + c];

    const int NT = NVOX / 64;    // 1024
    for(int tile = blockIdx.x; tile < NT; tile += gridDim.x){
        int rbase = tile * 64;
        // stage T tile hi/lo (all rows valid)
        {
            int row = tid >> 2, kseg = (tid & 3) * 16;
            const float4* fp = (const float4*)&T[(size_t)(rbase + row)*64 + kseg];
            float fv[16];
            *(float4*)&fv[0]  = fp[0];
            *(float4*)&fv[4]  = fp[1];
            *(float4*)&fv[8]  = fp[2];
            *(float4*)&fv[12] = fp[3];
            short hi[16], lo[16];
            #pragma unroll
            for(int j=0;j<16;++j){
                short h = f2bf_rne(fv[j]);
                hi[j] = h; lo[j] = f2bf_rne(fv[j] - bf2f(h));
            }
            #pragma unroll
            for(int i=0;i<4;++i){
                *(short4v*)&Ah[row*68 + kseg + 4*i] = *(short4v*)&hi[4*i];
                *(short4v*)&Al[row*68 + kseg + 4*i] = *(short4v*)&lo[4*i];
            }
        }
        if(tid < 64){
            int vox = rbase + tid;
            csh[tid] = (float)(vstart[vox+1] - vstart[vox]);
        }
        __syncthreads();
        f32x16 acc;
        #pragma unroll
        for(int i=0;i<16;++i) acc[i]=0.f;
        #pragma unroll
        for(int s=0;s<4;++s){
            int abase = (rowhalf + c)*68 + s*16 + g*4;
            short8v ah, al;
            ((short4v*)&ah)[0] = *(short4v*)&Ah[abase];
            ((short4v*)&ah)[1] = *(short4v*)&Ah[abase + 8];
            ((short4v*)&al)[0] = *(short4v*)&Al[abase];
            ((short4v*)&al)[1] = *(short4v*)&Al[abase + 8];
            acc = __builtin_amdgcn_mfma_f32_32x32x16_bf16(ah, wh[s], acc, 0,0,0);
            acc = __builtin_amdgcn_mfma_f32_32x32x16_bf16(al, wh[s], acc, 0,0,0);
            acc = __builtin_amdgcn_mfma_f32_32x32x16_bf16(ah, wl[s], acc, 0,0,0);
        }
        #pragma unroll
        for(int r=0;r<16;++r){
            int row = rowhalf + (r&3) + 8*(r>>2) + 4*g;
            float cv = csh[row];
            float rv = (cv > 0.f) ? 1.0f/cv : 0.f;
            float bz = (cv > 0.f) ? bo2c : 0.f;
            out[(size_t)(rbase + row)*64 + colhalf + c] = acc[r]*rv + bz;
        }
        __syncthreads();
    }
}

extern "C" void kernel_launch(void* const* d_in, const int* in_sizes, int n_in,
                              void* d_out, int out_size, void* d_ws, size_t ws_size,
                              hipStream_t stream) {
    if(ws_size < WS_NEEDED) return;

    const float* features = (const float*)d_in[0];
    const int*   coors    = (const int*)d_in[1];
    const int*   cif      = (const int*)d_in[2];
    const int*   scv      = (const int*)d_in[3];
    const float* W_in     = (const float*)d_in[4];
    const float* b_in     = (const float*)d_in[5];
    const float* W1       = (const float*)d_in[6];
    const float* b1       = (const float*)d_in[7];
    const float* g1       = (const float*)d_in[8];
    const float* be1      = (const float*)d_in[9];
    const float* W2       = (const float*)d_in[10];
    const float* b2       = (const float*)d_in[11];
    const float* g2       = (const float*)d_in[12];
    const float* be2      = (const float*)d_in[13];
    const float* W3       = (const float*)d_in[14];
    const float* b3       = (const float*)d_in[15];
    const float* Wo1      = (const float*)d_in[16];
    const float* bo1      = (const float*)d_in[17];
    const float* Wo2      = (const float*)d_in[18];
    const float* bo2      = (const float*)d_in[19];

    char* ws = (char*)d_ws;
    unsigned* bitmap = (unsigned*)(ws + OFF_BITMAP);
    float*    stats  = (float*)(ws + OFF_STATS);
    float*    cnt    = (float*)(ws + OFF_CNT);
    unsigned* vh     = (unsigned*)(ws + OFF_VH);
    unsigned short* yb = (unsigned short*)(ws + OFF_Y);
    float*    T      = (float*)(ws + OFF_T);        // aliases yb (dead after ppm2)
    unsigned short* P2 = (unsigned short*)(ws + OFF_P2);
    unsigned* pref   = (unsigned*)(ws + OFF_PREF);
    unsigned* bsum   = (unsigned*)(ws + OFF_BSUM);
    unsigned* boff   = (unsigned*)(ws + OFF_BOFF);
    unsigned* Ucnt   = (unsigned*)(ws + OFF_UCNT);
    int*      inv    = (int*)(ws + OFF_INV);
    unsigned short* P1 = (unsigned short*)(ws + OFF_P1);
    unsigned short* x2b = (unsigned short*)(ws + OFF_X2);
    int*      csr_j  = (int*)(ws + OFF_CSRJ);
    int*      csr_h  = (int*)(ws + OFF_CSRH);
    unsigned* vstart = (unsigned*)(ws + OFF_VSTART);
    unsigned* vnext  = (unsigned*)(ws + OFF_VNEXT);
    unsigned* vpart  = (unsigned*)(ws + OFF_VPART);
    unsigned* vbsum  = (unsigned*)(ws + OFF_VBSUM);

    hipMemsetAsync(d_ws, 0, ZERO_BYTES, stream);

    k_mark  <<<(N_FULL+255)/256, 256, 0, stream>>>(coors, scv, bitmap, vh);
    k_scanA <<<1024, 1024, 0, stream>>>(bitmap, pref, bsum);
    k_scanB <<<1, 1024, 0, stream>>>(bsum, boff, Ucnt);
    k_p1f   <<<1024, 256, 0, stream>>>(features, coors, bitmap, pref, boff,
                                       W_in, b_in, Wo1, W1, P1, inv, cnt, yb);
    // CSR build (overwrites bitmap/pref regions — safe after k_p1f)
    k_vscanA<<<64, 1024, 0, stream>>>(vh, vpart, vbsum);
    k_vfix  <<<64, 1024, 0, stream>>>(vpart, vbsum, vstart, vnext);
    k_fill  <<<(N_FULL+255)/256, 256, 0, stream>>>(cif, scv, inv, vnext, csr_j, csr_h);
    // PPmodel chain (BN finalize inlined into ppm2/ppm3)
    k_bn1   <<<1024, 256, 0, stream>>>(yb, cnt, Ucnt, b1, stats);
    k_ppm2  <<<1024, 256, 0, stream>>>(yb, cnt, Ucnt, W2, b1, b2, be1, g1, x2b, stats);
    k_ppm3  <<<1024, 256, 0, stream>>>(x2b, Ucnt, W3, b3, be2, g2, Wo1, P2, stats);
    // output stage: gather accumulate -> T, then fused GEMM + mean
    k_vox   <<<NVOX/16, 256, 0, stream>>>(vstart, csr_j, csr_h, P1, P2, bo1, T);
    k_wo2   <<<256, 256, 0, stream>>>(T, vstart, Wo2, bo2, (float*)d_out);
}